// Round 7
// baseline (399.245 us; speedup 1.0000x reference)
//
#include <hip/hip_runtime.h>
#include <stdint.h>

#define Bdim 16
#define Sdim 4096
#define Hdim 512
#define Mdim (Bdim*Sdim)      // 65536
#define N3   (3*Hdim)         // 1536
#define Kdim 512
#define NCHUNK 64
#define CLEN  (Sdim/NCHUNK)   // 64

typedef __bf16 bf16;
typedef __bf16 bf16x4 __attribute__((ext_vector_type(4)));
typedef __bf16 bf16x8 __attribute__((ext_vector_type(8)));
typedef float  f32x4  __attribute__((ext_vector_type(4)));
typedef _Float16 f16;
typedef _Float16 f16x4 __attribute__((ext_vector_type(4)));
typedef _Float16 f16x8 __attribute__((ext_vector_type(8)));

__device__ __forceinline__ void gload_lds16(const void* g, void* l) {
  __builtin_amdgcn_global_load_lds(
      (const __attribute__((address_space(1))) uint32_t*)g,
      (__attribute__((address_space(3))) uint32_t*)l, 16, 0, 0);
}

// ---------- fp32 -> bf16 convert (vectorized) ----------
__global__ void __launch_bounds__(256) cvt_kernel(const float4* __restrict__ in,
                                                  bf16x4* __restrict__ out, int n4) {
  int i = blockIdx.x * blockDim.x + threadIdx.x;
  if (i >= n4) return;
  float4 v = in[i];
  bf16x4 o;
  o.x = (bf16)v.x; o.y = (bf16)v.y; o.z = (bf16)v.z; o.w = (bf16)v.w;
  out[i] = o;
}

// ============ persistent 8-phase 256x256 MFMA GEMM, 6 items/block ==========
// grid=256 (1 block/CU). Item g = it*256 + bid -> mt=g/6, nt=g%6.
// Pipeline (BK=64, 2x64KB LDS dbuf, half-tile stream, 6-half lead) runs
// continuously across items: epilogue stages next item's halves 0-3 first,
// repacks C via the dead buf1 (2 x 64KB rounds, lgkmcnt-only barriers),
// stages halves 4-5, then gates on vmcnt(20) (=h0-3 landed).
#define BM 256
#define BN 256
#define BKT 64
#define NKT (Kdim/BKT)   // 8

__device__ __forceinline__ bf16x8 lds_ld(const char* p) { return *(const bf16x8*)p; }

__device__ __forceinline__ void read_af(bf16x8 (&d)[4][2], const char* Lb, uint32_t base,
                                        uint32_t swk0, uint32_t swk1, int mh) {
  #pragma unroll
  for (int i = 0; i < 4; ++i) {
    d[i][0] = lds_ld(Lb + base + mh * 8192 + i * 2048 + swk0);
    d[i][1] = lds_ld(Lb + base + mh * 8192 + i * 2048 + swk1);
  }
}
__device__ __forceinline__ void read_bf(bf16x8 (&d)[2][2], const char* Lb, uint32_t base,
                                        uint32_t swk0, uint32_t swk1, int nh) {
  #pragma unroll
  for (int j = 0; j < 2; ++j) {
    d[j][0] = lds_ld(Lb + base + nh * 4096 + j * 2048 + swk0);
    d[j][1] = lds_ld(Lb + base + nh * 4096 + j * 2048 + swk1);
  }
}
__device__ __forceinline__ void chunk16(f32x4 (&acc)[8][4], const bf16x8 (&a)[4][2],
                                        const bf16x8 (&b)[2][2], int mb, int nb) {
  __builtin_amdgcn_s_setprio(1);
  #pragma unroll
  for (int i = 0; i < 4; ++i)
    #pragma unroll
    for (int j = 0; j < 2; ++j)
      #pragma unroll
      for (int kk = 0; kk < 2; ++kk)
        acc[mb + i][nb + j] =
            __builtin_amdgcn_mfma_f32_16x16x32_bf16(a[i][kk], b[j][kk], acc[mb + i][nb + j], 0, 0, 0);
  __builtin_amdgcn_s_setprio(0);
}

// compile-time half-stage (within current item), half index H in [0,32)
template <int H>
__device__ __forceinline__ void stage_half(const bf16* Ag, const bf16* Bg, char* lds,
                                           uint32_t so0, uint32_t wbase) {
  if constexpr (H <= 4 * NKT - 1) {
    constexpr int th = H >> 2, ss = H & 3;
    constexpr uint32_t goff = (uint32_t)((ss >> 1) * 128 * Kdim + th * BKT);
    constexpr uint32_t lbase = (uint32_t)((th & 1) * 65536 + (ss & 1) * 32768 + (ss >> 1) * 16384);
    const bf16* gp = (ss & 1) ? Bg : Ag;
    gload_lds16(gp + goff + so0,         lds + lbase + wbase);
    gload_lds16(gp + goff + so0 + 32768, lds + lbase + 8192 + wbase);
  }
}
// runtime half-stage (next item's pointers)
__device__ __forceinline__ void stage_halfR(int th, int ss, const bf16* Ap, const bf16* Bp,
                                            char* lds, uint32_t so0, uint32_t wbase) {
  uint32_t goff  = (uint32_t)((ss >> 1) * 128 * Kdim + th * BKT);
  uint32_t lbase = (uint32_t)((th & 1) * 65536 + (ss & 1) * 32768 + (ss >> 1) * 16384);
  const bf16* gp = (ss & 1) ? Bp : Ap;
  gload_lds16(gp + goff + so0,         lds + lbase + wbase);
  gload_lds16(gp + goff + so0 + 32768, lds + lbase + 8192 + wbase);
}

#define BAR()   __builtin_amdgcn_s_barrier()
#define LGKM0() do { asm volatile("s_waitcnt lgkmcnt(0)" ::: "memory"); \
                     __builtin_amdgcn_sched_barrier(0); } while (0)

template <int T>
__device__ __forceinline__ void ktile(char* lds, f32x4 (&acc)[8][4],
    bf16x8 (&af0)[4][2], bf16x8 (&af1)[4][2], bf16x8 (&bf0)[2][2], bf16x8 (&bf1)[2][2],
    const bf16* Ag, const bf16* Bg, uint32_t so0, uint32_t wbase,
    uint32_t aBase, uint32_t bBase, uint32_t swk0, uint32_t swk1) {
  const char* Lb = lds + (T & 1) * 65536;
  // p0: (m-half0, n-half0)
  read_af(af0, Lb, aBase, swk0, swk1, 0);
  read_bf(bf0, Lb, bBase, swk0, swk1, 0);
  stage_half<4 * T + 6>(Ag, Bg, lds, so0, wbase);
  BAR(); LGKM0();
  chunk16(acc, af0, bf0, 0, 0);
  BAR();
  // p1: (m-half1, n-half0)
  read_af(af1, Lb, aBase, swk0, swk1, 1);
  stage_half<4 * T + 7>(Ag, Bg, lds, so0, wbase);
  BAR(); LGKM0();
  chunk16(acc, af1, bf0, 4, 0);
  BAR();
  // p2: (m-half1, n-half1)
  read_bf(bf1, Lb, bBase, swk0, swk1, 1);
  stage_half<4 * T + 8>(Ag, Bg, lds, so0, wbase);
  BAR(); LGKM0();
  chunk16(acc, af1, bf1, 4, 2);
  BAR();
  // p3: (m-half0, n-half1)
  stage_half<4 * T + 9>(Ag, Bg, lds, so0, wbase);
  BAR(); LGKM0();
  chunk16(acc, af0, bf1, 0, 2);
  if constexpr (T <= NKT - 3) {
    asm volatile("s_waitcnt vmcnt(4)" ::: "memory");  // tile T+1 fully landed
  } else if constexpr (T == NKT - 2) {
    asm volatile("s_waitcnt vmcnt(0)" ::: "memory");  // item's last tile landed
  }
  BAR();
}

__global__ void __launch_bounds__(512, 2) gemm_act_kernel(
    const bf16* __restrict__ A, const bf16* __restrict__ Wb,
    const float* __restrict__ bias,
    f16* __restrict__ zbuf, f16* __restrict__ fbuf, f16* __restrict__ ogbuf) {
  __shared__ char lds[131072];
  const int tid  = threadIdx.x;
  const int wid  = tid >> 6;
  const int lane = tid & 63;
  const int wr = wid >> 2, wc = wid & 3;   // 2(M) x 4(N) waves; wave tile 128x64
  const int bid = blockIdx.x;

  // staging addressing: thread covers rows r0 and r0+64 of a half, slot=tid&7
  const uint32_t r0   = tid >> 3;
  const uint32_t slot = tid & 7;
  const uint32_t so0  = r0 * Kdim + ((slot ^ (r0 & 7)) << 3);  // elements
  const uint32_t wbase = (uint32_t)(wid * 1024);               // bytes (LDS dest)
  // ds_read addressing (within 64KB buffer)
  const uint32_t kslot = lane >> 4;
  const uint32_t swk0 = ((kslot)     ^ (uint32_t)(lane & 7)) << 4;
  const uint32_t swk1 = ((4 + kslot) ^ (uint32_t)(lane & 7)) << 4;
  const uint32_t aBase = (uint32_t)((wr * 128 + (lane & 15)) * 128);
  const uint32_t bBase = (uint32_t)(32768 + (wc * 64 + (lane & 15)) * 128);

  bf16x8 af0[4][2], af1[4][2], bf0[2][2], bf1[2][2];

  // ---- prologue: item 0 (g = bid), stage halves 0..5 ----
  {
    uint32_t g0 = (uint32_t)bid;
    uint32_t mt0 = g0 / 6;
    uint32_t nt0 = g0 - 6 * mt0;
    const bf16* Ag = A  + (size_t)mt0 * BM * Kdim;
    const bf16* Bg = Wb + (size_t)nt0 * BN * Kdim;
    stage_half<0>(Ag, Bg, lds, so0, wbase);
    stage_half<1>(Ag, Bg, lds, so0, wbase);
    stage_half<2>(Ag, Bg, lds, so0, wbase);
    stage_half<3>(Ag, Bg, lds, so0, wbase);
    stage_half<4>(Ag, Bg, lds, so0, wbase);
    stage_half<5>(Ag, Bg, lds, so0, wbase);
    asm volatile("s_waitcnt vmcnt(4)" ::: "memory");  // h0-3 landed
    BAR();
  }

  #pragma unroll 1
  for (int it = 0; it < 6; ++it) {
    const uint32_t g  = (uint32_t)(it * 256 + bid);
    const uint32_t mt = g / 6;
    const uint32_t nt = g - 6 * mt;
    const int row0 = (int)mt * BM;
    const bf16* Ag = A  + (size_t)mt * BM * Kdim;
    const bf16* Bg = Wb + (size_t)nt * BN * Kdim;

    f32x4 acc[8][4];
    #pragma unroll
    for (int m = 0; m < 8; ++m)
      #pragma unroll
      for (int n = 0; n < 4; ++n)
        acc[m][n] = (f32x4){0.f, 0.f, 0.f, 0.f};

    ktile<0>(lds, acc, af0, af1, bf0, bf1, Ag, Bg, so0, wbase, aBase, bBase, swk0, swk1);
    ktile<1>(lds, acc, af0, af1, bf0, bf1, Ag, Bg, so0, wbase, aBase, bBase, swk0, swk1);
    ktile<2>(lds, acc, af0, af1, bf0, bf1, Ag, Bg, so0, wbase, aBase, bBase, swk0, swk1);
    ktile<3>(lds, acc, af0, af1, bf0, bf1, Ag, Bg, so0, wbase, aBase, bBase, swk0, swk1);
    ktile<4>(lds, acc, af0, af1, bf0, bf1, Ag, Bg, so0, wbase, aBase, bBase, swk0, swk1);
    ktile<5>(lds, acc, af0, af1, bf0, bf1, Ag, Bg, so0, wbase, aBase, bBase, swk0, swk1);
    ktile<6>(lds, acc, af0, af1, bf0, bf1, Ag, Bg, so0, wbase, aBase, bBase, swk0, swk1);
    ktile<7>(lds, acc, af0, af1, bf0, bf1, Ag, Bg, so0, wbase, aBase, bBase, swk0, swk1);
    // after ktile<7>: vmcnt=0 (drained at T=6), lgkm retired, all waves barriered.

    // ---- epilogue (overlapped with next item's staging lead) ----
    const int gate = (int)(nt >> 1);
    const int cbn  = (int)(nt & 1) * 256;
    f16* dst = (gate == 0) ? zbuf : ((gate == 1) ? fbuf : ogbuf);
    float bv[4];
    #pragma unroll
    for (int n = 0; n < 4; ++n)
      bv[n] = bias[gate * Hdim + cbn + wc * 64 + n * 16 + (lane & 15)];

    const bool stageNext = (it < 5);
    const bf16* AgN = A; const bf16* BgN = Wb;
    if (stageNext) {
      uint32_t gN  = g + 256;
      uint32_t mtN = gN / 6;
      uint32_t ntN = gN - 6 * mtN;
      AgN = A  + (size_t)mtN * BM * Kdim;
      BgN = Wb + (size_t)ntN * BN * Kdim;
      stage_halfR(0, 0, AgN, BgN, lds, so0, wbase);  // h0
      stage_halfR(0, 1, AgN, BgN, lds, so0, wbase);  // h1
      stage_halfR(0, 2, AgN, BgN, lds, so0, wbase);  // h2
      stage_halfR(0, 3, AgN, BgN, lds, so0, wbase);  // h3
    }

    char* scr = lds + 65536;  // buf1 (dead: tile7 reads retired) as repack scratch
    #pragma unroll
    for (int R = 0; R < 2; ++R) {
      // write: acc m = 4R..4R+3 -> 128 local rows x 512B, swizzled
      #pragma unroll
      for (int m4 = 0; m4 < 4; ++m4) {
        const int m = R * 4 + m4;
        #pragma unroll
        for (int n = 0; n < 4; ++n) {
          int col = wc * 64 + n * 16 + (lane & 15);
          #pragma unroll
          for (int r = 0; r < 4; ++r) {
            int Lrow = wr * 64 + m4 * 16 + (lane >> 4) * 4 + r;
            float y = acc[m][n][r] + bv[n];
            float v;
            if (gate == 0) {                       // tanh(y) = 1 - 2/(e^{2y}+1)
              float e = __expf(2.f * y);
              v = 1.f - 2.f / (e + 1.f);
            } else {                               // sigmoid
              v = 1.f / (1.f + __expf(-y));
            }
            uint32_t byte = (uint32_t)(Lrow * 512 + col * 2) ^ ((uint32_t)(Lrow & 7) << 4);
            *(f16*)(scr + byte) = (f16)v;
          }
        }
      }
      asm volatile("s_waitcnt lgkmcnt(0)" ::: "memory");
      BAR();
      // read + coalesced stores (no vmcnt drain -- staged halves stay in flight)
      #pragma unroll
      for (int j = 0; j < 8; ++j) {
        int c = j * 512 + tid;
        int Lrow = c >> 5, col8 = c & 31;
        uint32_t byte = (uint32_t)(Lrow * 512 + col8 * 16) ^ ((uint32_t)(Lrow & 7) << 4);
        f16x8 v = *(const f16x8*)(scr + byte);
        int G = (Lrow >> 6) * 128 + R * 64 + (Lrow & 63);
        *(f16x8*)&dst[(size_t)(row0 + G) * Hdim + cbn + col8 * 8] = v;
      }
      asm volatile("s_waitcnt lgkmcnt(0)" ::: "memory");
      BAR();  // WAR: reads retired before next round's writes / h4-h5 staging
    }

    if (stageNext) {
      stage_halfR(1, 0, AgN, BgN, lds, so0, wbase);  // h4 (buf1 A-region)
      stage_halfR(1, 1, AgN, BgN, lds, so0, wbase);  // h5 (buf1 B-region)
      // queue: [bias 4][h0-3 8][R0 stores 8][R1 stores 8][h4-5 4] -> h0-3 landed:
      asm volatile("s_waitcnt vmcnt(20)" ::: "memory");
      BAR();
    }
  }
}

// ---------- scan pass A: per-chunk composite (P = prod(1-f), Q = local scan) ----------
__global__ void __launch_bounds__(256) scanA_kernel(const f16x4* __restrict__ z4,
                                                    const f16x4* __restrict__ f4,
                                                    float* __restrict__ Pb,
                                                    float* __restrict__ Qb) {
  int u  = blockIdx.x * blockDim.x + threadIdx.x;  // 131072 = NCHUNK*B*128
  int hq = u & 127;
  int bc = u >> 7;
  int b  = bc & (Bdim - 1);
  int c  = bc >> 4;
  size_t base = ((size_t)(b * Sdim + c * CLEN)) * 128 + hq;  // in quads
  float P[4] = {1.f, 1.f, 1.f, 1.f}, Q[4] = {0.f, 0.f, 0.f, 0.f};
  #pragma unroll 4
  for (int s = 0; s < CLEN; ++s) {
    f16x4 fv = f4[base], zv = z4[base];
    #pragma unroll
    for (int j = 0; j < 4; ++j) {
      float f = (float)fv[j];
      Q[j] += f * ((float)zv[j] - Q[j]);
      P[j] *= (1.f - f);
    }
    base += 128;
  }
  int outi = ((c * Bdim + b) << 9) + hq * 4;
  *(float4*)&Pb[outi] = make_float4(P[0], P[1], P[2], P[3]);
  *(float4*)&Qb[outi] = make_float4(Q[0], Q[1], Q[2], Q[3]);
}

// ---------- scan pass B: scan chunk composites -> h_in per chunk + c_last ----------
__global__ void __launch_bounds__(256) scanB_kernel(const float* __restrict__ Pb,
                                                    const float* __restrict__ Qb,
                                                    float* __restrict__ hin,
                                                    float* __restrict__ c_last) {
  int t = blockIdx.x * blockDim.x + threadIdx.x;  // 8192 = B*H
  int h = t & (Hdim - 1), b = t >> 9;
  float hs = 0.f;
  #pragma unroll 8
  for (int c = 0; c < NCHUNK; ++c) {
    hin[c * (Bdim * Hdim) + t] = hs;
    int u = ((c * Bdim + b) << 9) + h;
    hs = Pb[u] * hs + Qb[u];
  }
  c_last[t] = hs;
}

// ---------- scan pass C: rerun chunk with correct h_in, fuse out = og * h ----------
__global__ void __launch_bounds__(256) scanC_kernel(const f16x4* __restrict__ z4,
                                                    const f16x4* __restrict__ f4,
                                                    const f16x4* __restrict__ og4,
                                                    const float* __restrict__ hin,
                                                    float4* __restrict__ out4) {
  int u  = blockIdx.x * blockDim.x + threadIdx.x;
  int hq = u & 127;
  int bc = u >> 7;
  int b  = bc & (Bdim - 1);
  int c  = bc >> 4;
  float4 hv = *(const float4*)&hin[c * (Bdim * Hdim) + b * Hdim + hq * 4];
  float h[4] = {hv.x, hv.y, hv.z, hv.w};
  size_t base = ((size_t)(b * Sdim + c * CLEN)) * 128 + hq;
  #pragma unroll 4
  for (int s = 0; s < CLEN; ++s) {
    f16x4 fv = f4[base], zv = z4[base], ov = og4[base];
    float4 o;
    #pragma unroll
    for (int j = 0; j < 4; ++j) {
      h[j] += (float)fv[j] * ((float)zv[j] - h[j]);
    }
    o.x = (float)ov[0] * h[0]; o.y = (float)ov[1] * h[1];
    o.z = (float)ov[2] * h[2]; o.w = (float)ov[3] * h[3];
    out4[base] = o;
    base += 128;
  }
}

extern "C" void kernel_launch(void* const* d_in, const int* in_sizes, int n_in,
                              void* d_out, int out_size, void* d_ws, size_t ws_size,
                              hipStream_t stream) {
  const float* inp  = (const float*)d_in[0];
  const float* W    = (const float*)d_in[1];
  const float* bias = (const float*)d_in[2];
  float* out = (float*)d_out;

  char* ws = (char*)d_ws;
  // workspace layout (bytes), total ~276 MB
  bf16* Abf = (bf16*)(ws);                   //  67,108,864
  bf16* Wbf = (bf16*)(ws + 67108864);        //   1,572,864
  f16*  zh  = (f16*) (ws + 68681728);        //  67,108,864
  f16*  fh  = (f16*) (ws + 135790592);       //  67,108,864
  f16*  ogh = (f16*) (ws + 202899456);       //  67,108,864
  float* Pb = (float*)(ws + 270008320);      //   2,097,152
  float* Qb = (float*)(ws + 272105472);      //   2,097,152
  float* hin= (float*)(ws + 274202624);      //   2,097,152

  // 1) convert inp and W to bf16
  {
    int n4 = (Mdim * Kdim) / 4;  // 8,388,608
    cvt_kernel<<<n4 / 256, 256, 0, stream>>>((const float4*)inp, (bf16x4*)Abf, n4);
  }
  {
    int n4 = (N3 * Kdim) / 4;    // 196,608
    cvt_kernel<<<n4 / 256, 256, 0, stream>>>((const float4*)W, (bf16x4*)Wbf, n4);
  }
  // 2) persistent GEMM + bias + activations -> fp16 gates (grid = 256 = 1/CU)
  gemm_act_kernel<<<256, 512, 0, stream>>>(Abf, Wbf, bias, zh, fh, ogh);
  // 3) chunked linear-recurrence scan
  scanA_kernel<<<(NCHUNK * Bdim * 128) / 256, 256, 0, stream>>>(
      (const f16x4*)zh, (const f16x4*)fh, Pb, Qb);
  scanB_kernel<<<(Bdim * Hdim) / 256, 256, 0, stream>>>(Pb, Qb, hin,
                                                        out + (size_t)Mdim * Hdim);
  scanC_kernel<<<(NCHUNK * Bdim * 128) / 256, 256, 0, stream>>>(
      (const f16x4*)zh, (const f16x4*)fh, (const f16x4*)ogh, hin, (float4*)out);
}

// Round 8
// 388.859 us; speedup vs baseline: 1.0267x; 1.0267x over previous
//
#include <hip/hip_runtime.h>
#include <stdint.h>

#define Bdim 16
#define Sdim 4096
#define Hdim 512
#define Mdim (Bdim*Sdim)      // 65536
#define N3   (3*Hdim)         // 1536
#define Kdim 512
#define NCHUNK 64
#define CLEN  (Sdim/NCHUNK)   // 64

typedef __bf16 bf16;
typedef __bf16 bf16x4 __attribute__((ext_vector_type(4)));
typedef __bf16 bf16x8 __attribute__((ext_vector_type(8)));
typedef float  f32x4  __attribute__((ext_vector_type(4)));
typedef _Float16 f16;
typedef _Float16 f16x4 __attribute__((ext_vector_type(4)));
typedef _Float16 f16x8 __attribute__((ext_vector_type(8)));

__device__ __forceinline__ void gload_lds16(const void* g, void* l) {
  __builtin_amdgcn_global_load_lds(
      (const __attribute__((address_space(1))) uint32_t*)g,
      (__attribute__((address_space(3))) uint32_t*)l, 16, 0, 0);
}

// ---------- fp32 -> bf16 convert (vectorized) ----------
__global__ void __launch_bounds__(256) cvt_kernel(const float4* __restrict__ in,
                                                  bf16x4* __restrict__ out, int n4) {
  int i = blockIdx.x * blockDim.x + threadIdx.x;
  if (i >= n4) return;
  float4 v = in[i];
  bf16x4 o;
  o.x = (bf16)v.x; o.y = (bf16)v.y; o.z = (bf16)v.z; o.w = (bf16)v.w;
  out[i] = o;
}

// ====== persistent 8-phase 256x256 MFMA GEMM, XCD-local item schedule ======
// grid=256 (1 block/CU). x=bid%8 (XCD), l=bid/8. Item g = x*192 + it*32 + l:
// the 6 blocks sharing an A-panel (same g/6) are consecutive l on ONE XCD ->
// panel read once into that XCD's L2. Per-XCD round set ~3.3MB < 4MB L2.
// Pipeline (BK=64, 2x64KB dbuf, half-tile stream, 6-half lead) persists
// across items: epilogue = bias loads, h0-3 issue, LDS repack (lgkm-only
// barriers), h4-5 issue, vmcnt(4) (stores+h0-3 drained, h4-5 in flight).
#define BM 256
#define BN 256
#define BKT 64
#define NKT (Kdim/BKT)   // 8

__device__ __forceinline__ bf16x8 lds_ld(const char* p) { return *(const bf16x8*)p; }

__device__ __forceinline__ void read_af(bf16x8 (&d)[4][2], const char* Lb, uint32_t base,
                                        uint32_t swk0, uint32_t swk1, int mh) {
  #pragma unroll
  for (int i = 0; i < 4; ++i) {
    d[i][0] = lds_ld(Lb + base + mh * 8192 + i * 2048 + swk0);
    d[i][1] = lds_ld(Lb + base + mh * 8192 + i * 2048 + swk1);
  }
}
__device__ __forceinline__ void read_bf(bf16x8 (&d)[2][2], const char* Lb, uint32_t base,
                                        uint32_t swk0, uint32_t swk1, int nh) {
  #pragma unroll
  for (int j = 0; j < 2; ++j) {
    d[j][0] = lds_ld(Lb + base + nh * 4096 + j * 2048 + swk0);
    d[j][1] = lds_ld(Lb + base + nh * 4096 + j * 2048 + swk1);
  }
}
__device__ __forceinline__ void chunk16(f32x4 (&acc)[8][4], const bf16x8 (&a)[4][2],
                                        const bf16x8 (&b)[2][2], int mb, int nb) {
  __builtin_amdgcn_s_setprio(1);
  #pragma unroll
  for (int i = 0; i < 4; ++i)
    #pragma unroll
    for (int j = 0; j < 2; ++j)
      #pragma unroll
      for (int kk = 0; kk < 2; ++kk)
        acc[mb + i][nb + j] =
            __builtin_amdgcn_mfma_f32_16x16x32_bf16(a[i][kk], b[j][kk], acc[mb + i][nb + j], 0, 0, 0);
  __builtin_amdgcn_s_setprio(0);
}

// compile-time half-stage (within current item), half index H in [0,32)
template <int H>
__device__ __forceinline__ void stage_half(const bf16* Ag, const bf16* Bg, char* lds,
                                           uint32_t so0, uint32_t wbase) {
  if constexpr (H <= 4 * NKT - 1) {
    constexpr int th = H >> 2, ss = H & 3;
    constexpr uint32_t goff = (uint32_t)((ss >> 1) * 128 * Kdim + th * BKT);
    constexpr uint32_t lbase = (uint32_t)((th & 1) * 65536 + (ss & 1) * 32768 + (ss >> 1) * 16384);
    const bf16* gp = (ss & 1) ? Bg : Ag;
    gload_lds16(gp + goff + so0,         lds + lbase + wbase);
    gload_lds16(gp + goff + so0 + 32768, lds + lbase + 8192 + wbase);
  }
}
// runtime half-stage (next item's pointers)
__device__ __forceinline__ void stage_halfR(int th, int ss, const bf16* Ap, const bf16* Bp,
                                            char* lds, uint32_t so0, uint32_t wbase) {
  uint32_t goff  = (uint32_t)((ss >> 1) * 128 * Kdim + th * BKT);
  uint32_t lbase = (uint32_t)((th & 1) * 65536 + (ss & 1) * 32768 + (ss >> 1) * 16384);
  const bf16* gp = (ss & 1) ? Bp : Ap;
  gload_lds16(gp + goff + so0,         lds + lbase + wbase);
  gload_lds16(gp + goff + so0 + 32768, lds + lbase + 8192 + wbase);
}

#define BAR()   __builtin_amdgcn_s_barrier()
#define LGKM0() do { asm volatile("s_waitcnt lgkmcnt(0)" ::: "memory"); \
                     __builtin_amdgcn_sched_barrier(0); } while (0)

template <int T>
__device__ __forceinline__ void ktile(char* lds, f32x4 (&acc)[8][4],
    bf16x8 (&af0)[4][2], bf16x8 (&af1)[4][2], bf16x8 (&bf0)[2][2], bf16x8 (&bf1)[2][2],
    const bf16* Ag, const bf16* Bg, uint32_t so0, uint32_t wbase,
    uint32_t aBase, uint32_t bBase, uint32_t swk0, uint32_t swk1) {
  const char* Lb = lds + (T & 1) * 65536;
  // p0: (m-half0, n-half0)
  read_af(af0, Lb, aBase, swk0, swk1, 0);
  read_bf(bf0, Lb, bBase, swk0, swk1, 0);
  stage_half<4 * T + 6>(Ag, Bg, lds, so0, wbase);
  BAR(); LGKM0();
  chunk16(acc, af0, bf0, 0, 0);
  BAR();
  // p1: (m-half1, n-half0)
  read_af(af1, Lb, aBase, swk0, swk1, 1);
  stage_half<4 * T + 7>(Ag, Bg, lds, so0, wbase);
  BAR(); LGKM0();
  chunk16(acc, af1, bf0, 4, 0);
  BAR();
  // p2: (m-half1, n-half1)
  read_bf(bf1, Lb, bBase, swk0, swk1, 1);
  stage_half<4 * T + 8>(Ag, Bg, lds, so0, wbase);
  BAR(); LGKM0();
  chunk16(acc, af1, bf1, 4, 2);
  BAR();
  // p3: (m-half0, n-half1)
  stage_half<4 * T + 9>(Ag, Bg, lds, so0, wbase);
  BAR(); LGKM0();
  chunk16(acc, af0, bf1, 0, 2);
  if constexpr (T <= NKT - 3) {
    asm volatile("s_waitcnt vmcnt(4)" ::: "memory");  // tile T+1 fully landed
  } else if constexpr (T == NKT - 2) {
    asm volatile("s_waitcnt vmcnt(0)" ::: "memory");  // item's last tile landed
  }
  BAR();
}

__global__ void __launch_bounds__(512, 2) gemm_act_kernel(
    const bf16* __restrict__ A, const bf16* __restrict__ Wb,
    const float* __restrict__ bias,
    f16* __restrict__ zbuf, f16* __restrict__ fbuf, f16* __restrict__ ogbuf) {
  __shared__ char lds[131072];
  const int tid  = threadIdx.x;
  const int wid  = tid >> 6;
  const int lane = tid & 63;
  const int wr = wid >> 2, wc = wid & 3;   // 2(M) x 4(N) waves; wave tile 128x64
  const int bid = blockIdx.x;
  const int xcd = bid & 7;                 // bid%8 == XCD (round-robin dispatch)
  const int lcl = bid >> 3;                // 0..31 within XCD

  // staging addressing: thread covers rows r0 and r0+64 of a half, slot=tid&7
  const uint32_t r0   = tid >> 3;
  const uint32_t slot = tid & 7;
  const uint32_t so0  = r0 * Kdim + ((slot ^ (r0 & 7)) << 3);  // elements
  const uint32_t wbase = (uint32_t)(wid * 1024);               // bytes (LDS dest)
  // ds_read addressing (within 64KB buffer)
  const uint32_t kslot = lane >> 4;
  const uint32_t swk0 = ((kslot)     ^ (uint32_t)(lane & 7)) << 4;
  const uint32_t swk1 = ((4 + kslot) ^ (uint32_t)(lane & 7)) << 4;
  const uint32_t aBase = (uint32_t)((wr * 128 + (lane & 15)) * 128);
  const uint32_t bBase = (uint32_t)(32768 + (wc * 64 + (lane & 15)) * 128);

  bf16x8 af0[4][2], af1[4][2], bf0[2][2], bf1[2][2];

  // ---- prologue: item it=0 (g = xcd*192 + lcl), stage halves 0..5 ----
  {
    uint32_t g0 = (uint32_t)(xcd * 192 + lcl);
    uint32_t mt0 = g0 / 6;
    uint32_t nt0 = g0 - 6 * mt0;
    const bf16* Ag = A  + (size_t)mt0 * BM * Kdim;
    const bf16* Bg = Wb + (size_t)nt0 * BN * Kdim;
    stage_half<0>(Ag, Bg, lds, so0, wbase);
    stage_half<1>(Ag, Bg, lds, so0, wbase);
    stage_half<2>(Ag, Bg, lds, so0, wbase);
    stage_half<3>(Ag, Bg, lds, so0, wbase);
    stage_half<4>(Ag, Bg, lds, so0, wbase);
    stage_half<5>(Ag, Bg, lds, so0, wbase);
    asm volatile("s_waitcnt vmcnt(4)" ::: "memory");  // h0-3 landed
    BAR();
  }

  #pragma unroll 1
  for (int it = 0; it < 6; ++it) {
    const uint32_t g  = (uint32_t)(xcd * 192 + it * 32 + lcl);
    const uint32_t mt = g / 6;
    const uint32_t nt = g - 6 * mt;
    const int row0 = (int)mt * BM;
    const bf16* Ag = A  + (size_t)mt * BM * Kdim;
    const bf16* Bg = Wb + (size_t)nt * BN * Kdim;

    f32x4 acc[8][4];
    #pragma unroll
    for (int m = 0; m < 8; ++m)
      #pragma unroll
      for (int n = 0; n < 4; ++n)
        acc[m][n] = (f32x4){0.f, 0.f, 0.f, 0.f};

    ktile<0>(lds, acc, af0, af1, bf0, bf1, Ag, Bg, so0, wbase, aBase, bBase, swk0, swk1);
    ktile<1>(lds, acc, af0, af1, bf0, bf1, Ag, Bg, so0, wbase, aBase, bBase, swk0, swk1);
    ktile<2>(lds, acc, af0, af1, bf0, bf1, Ag, Bg, so0, wbase, aBase, bBase, swk0, swk1);
    ktile<3>(lds, acc, af0, af1, bf0, bf1, Ag, Bg, so0, wbase, aBase, bBase, swk0, swk1);
    ktile<4>(lds, acc, af0, af1, bf0, bf1, Ag, Bg, so0, wbase, aBase, bBase, swk0, swk1);
    ktile<5>(lds, acc, af0, af1, bf0, bf1, Ag, Bg, so0, wbase, aBase, bBase, swk0, swk1);
    ktile<6>(lds, acc, af0, af1, bf0, bf1, Ag, Bg, so0, wbase, aBase, bBase, swk0, swk1);
    ktile<7>(lds, acc, af0, af1, bf0, bf1, Ag, Bg, so0, wbase, aBase, bBase, swk0, swk1);
    // after ktile<7>: vmcnt=0 (drained at T=6), lgkm retired, all waves barriered.

    // ---- epilogue (overlapped with next item's staging lead) ----
    const int gate = (int)(nt >> 1);
    const int cbn  = (int)(nt & 1) * 256;
    f16* dst = (gate == 0) ? zbuf : ((gate == 1) ? fbuf : ogbuf);
    float bv[4];
    #pragma unroll
    for (int n = 0; n < 4; ++n)
      bv[n] = bias[gate * Hdim + cbn + wc * 64 + n * 16 + (lane & 15)];  // before h0-3!

    const bool stageNext = (it < 5);
    const bf16* AgN = A; const bf16* BgN = Wb;
    if (stageNext) {
      uint32_t gN  = g + 32;                 // next item on SAME XCD
      uint32_t mtN = gN / 6;
      uint32_t ntN = gN - 6 * mtN;
      AgN = A  + (size_t)mtN * BM * Kdim;
      BgN = Wb + (size_t)ntN * BN * Kdim;
      stage_halfR(0, 0, AgN, BgN, lds, so0, wbase);  // h0 (buf0: tile6 reads retired)
      stage_halfR(0, 1, AgN, BgN, lds, so0, wbase);  // h1
      stage_halfR(0, 2, AgN, BgN, lds, so0, wbase);  // h2
      stage_halfR(0, 3, AgN, BgN, lds, so0, wbase);  // h3
    }

    char* scr = lds + 65536;  // buf1 (dead: tile7 reads retired) as repack scratch
    #pragma unroll
    for (int R = 0; R < 2; ++R) {
      // write: acc m = 4R..4R+3 -> 128 local rows x 512B, swizzled
      #pragma unroll
      for (int m4 = 0; m4 < 4; ++m4) {
        const int m = R * 4 + m4;
        #pragma unroll
        for (int n = 0; n < 4; ++n) {
          int col = wc * 64 + n * 16 + (lane & 15);
          #pragma unroll
          for (int r = 0; r < 4; ++r) {
            int Lrow = wr * 64 + m4 * 16 + (lane >> 4) * 4 + r;
            float y = acc[m][n][r] + bv[n];
            float v;
            if (gate == 0) {                       // tanh(y) = 1 - 2/(e^{2y}+1)
              float e = __expf(2.f * y);
              v = 1.f - 2.f / (e + 1.f);
            } else {                               // sigmoid
              v = 1.f / (1.f + __expf(-y));
            }
            uint32_t byte = (uint32_t)(Lrow * 512 + col * 2) ^ ((uint32_t)(Lrow & 7) << 4);
            *(f16*)(scr + byte) = (f16)v;
          }
        }
      }
      asm volatile("s_waitcnt lgkmcnt(0)" ::: "memory");
      BAR();
      // read + coalesced stores (no vmcnt drain -- staged halves stay in flight)
      #pragma unroll
      for (int j = 0; j < 8; ++j) {
        int c = j * 512 + tid;
        int Lrow = c >> 5, col8 = c & 31;
        uint32_t byte = (uint32_t)(Lrow * 512 + col8 * 16) ^ ((uint32_t)(Lrow & 7) << 4);
        f16x8 v = *(const f16x8*)(scr + byte);
        int G = (Lrow >> 6) * 128 + R * 64 + (Lrow & 63);
        *(f16x8*)&dst[(size_t)(row0 + G) * Hdim + cbn + col8 * 8] = v;
      }
      asm volatile("s_waitcnt lgkmcnt(0)" ::: "memory");
      BAR();  // WAR: reads retired before next round's writes / h4-h5 staging
    }

    if (stageNext) {
      stage_halfR(1, 0, AgN, BgN, lds, so0, wbase);  // h4 (buf1 A-region)
      stage_halfR(1, 1, AgN, BgN, lds, so0, wbase);  // h5 (buf1 B-region)
      // drain bias+h0-3+all 16 stores; leave h4-5 (4 ops) in flight.
      // Once per item (~store latency), restores the K-loop vmcnt invariant.
      asm volatile("s_waitcnt vmcnt(4)" ::: "memory");
      BAR();
    }
  }
}

// ---------- scan pass A: per-chunk composite (P = prod(1-f), Q = local scan) ----------
__global__ void __launch_bounds__(256) scanA_kernel(const f16x4* __restrict__ z4,
                                                    const f16x4* __restrict__ f4,
                                                    float* __restrict__ Pb,
                                                    float* __restrict__ Qb) {
  int u  = blockIdx.x * blockDim.x + threadIdx.x;  // 131072 = NCHUNK*B*128
  int hq = u & 127;
  int bc = u >> 7;
  int b  = bc & (Bdim - 1);
  int c  = bc >> 4;
  size_t base = ((size_t)(b * Sdim + c * CLEN)) * 128 + hq;  // in quads
  float P[4] = {1.f, 1.f, 1.f, 1.f}, Q[4] = {0.f, 0.f, 0.f, 0.f};
  #pragma unroll 4
  for (int s = 0; s < CLEN; ++s) {
    f16x4 fv = f4[base], zv = z4[base];
    #pragma unroll
    for (int j = 0; j < 4; ++j) {
      float f = (float)fv[j];
      Q[j] += f * ((float)zv[j] - Q[j]);
      P[j] *= (1.f - f);
    }
    base += 128;
  }
  int outi = ((c * Bdim + b) << 9) + hq * 4;
  *(float4*)&Pb[outi] = make_float4(P[0], P[1], P[2], P[3]);
  *(float4*)&Qb[outi] = make_float4(Q[0], Q[1], Q[2], Q[3]);
}

// ---------- scan pass B: scan chunk composites -> h_in per chunk + c_last ----------
__global__ void __launch_bounds__(256) scanB_kernel(const float* __restrict__ Pb,
                                                    const float* __restrict__ Qb,
                                                    float* __restrict__ hin,
                                                    float* __restrict__ c_last) {
  int t = blockIdx.x * blockDim.x + threadIdx.x;  // 8192 = B*H
  int h = t & (Hdim - 1), b = t >> 9;
  float hs = 0.f;
  #pragma unroll 8
  for (int c = 0; c < NCHUNK; ++c) {
    hin[c * (Bdim * Hdim) + t] = hs;
    int u = ((c * Bdim + b) << 9) + h;
    hs = Pb[u] * hs + Qb[u];
  }
  c_last[t] = hs;
}

// ---------- scan pass C: rerun chunk with correct h_in, fuse out = og * h ----------
__global__ void __launch_bounds__(256) scanC_kernel(const f16x4* __restrict__ z4,
                                                    const f16x4* __restrict__ f4,
                                                    const f16x4* __restrict__ og4,
                                                    const float* __restrict__ hin,
                                                    float4* __restrict__ out4) {
  int u  = blockIdx.x * blockDim.x + threadIdx.x;
  int hq = u & 127;
  int bc = u >> 7;
  int b  = bc & (Bdim - 1);
  int c  = bc >> 4;
  float4 hv = *(const float4*)&hin[c * (Bdim * Hdim) + b * Hdim + hq * 4];
  float h[4] = {hv.x, hv.y, hv.z, hv.w};
  size_t base = ((size_t)(b * Sdim + c * CLEN)) * 128 + hq;
  #pragma unroll 4
  for (int s = 0; s < CLEN; ++s) {
    f16x4 fv = f4[base], zv = z4[base], ov = og4[base];
    float4 o;
    #pragma unroll
    for (int j = 0; j < 4; ++j) {
      h[j] += (float)fv[j] * ((float)zv[j] - h[j]);
    }
    o.x = (float)ov[0] * h[0]; o.y = (float)ov[1] * h[1];
    o.z = (float)ov[2] * h[2]; o.w = (float)ov[3] * h[3];
    out4[base] = o;
    base += 128;
  }
}

extern "C" void kernel_launch(void* const* d_in, const int* in_sizes, int n_in,
                              void* d_out, int out_size, void* d_ws, size_t ws_size,
                              hipStream_t stream) {
  const float* inp  = (const float*)d_in[0];
  const float* W    = (const float*)d_in[1];
  const float* bias = (const float*)d_in[2];
  float* out = (float*)d_out;

  char* ws = (char*)d_ws;
  // workspace layout (bytes), total ~276 MB
  bf16* Abf = (bf16*)(ws);                   //  67,108,864
  bf16* Wbf = (bf16*)(ws + 67108864);        //   1,572,864
  f16*  zh  = (f16*) (ws + 68681728);        //  67,108,864
  f16*  fh  = (f16*) (ws + 135790592);       //  67,108,864
  f16*  ogh = (f16*) (ws + 202899456);       //  67,108,864
  float* Pb = (float*)(ws + 270008320);      //   2,097,152
  float* Qb = (float*)(ws + 272105472);      //   2,097,152
  float* hin= (float*)(ws + 274202624);      //   2,097,152

  // 1) convert inp and W to bf16
  {
    int n4 = (Mdim * Kdim) / 4;  // 8,388,608
    cvt_kernel<<<n4 / 256, 256, 0, stream>>>((const float4*)inp, (bf16x4*)Abf, n4);
  }
  {
    int n4 = (N3 * Kdim) / 4;    // 196,608
    cvt_kernel<<<n4 / 256, 256, 0, stream>>>((const float4*)W, (bf16x4*)Wbf, n4);
  }
  // 2) persistent GEMM + bias + activations -> fp16 gates (grid = 256 = 1/CU)
  gemm_act_kernel<<<256, 512, 0, stream>>>(Abf, Wbf, bias, zh, fh, ogh);
  // 3) chunked linear-recurrence scan
  scanA_kernel<<<(NCHUNK * Bdim * 128) / 256, 256, 0, stream>>>(
      (const f16x4*)zh, (const f16x4*)fh, Pb, Qb);
  scanB_kernel<<<(Bdim * Hdim) / 256, 256, 0, stream>>>(Pb, Qb, hin,
                                                        out + (size_t)Mdim * Hdim);
  scanC_kernel<<<(NCHUNK * Bdim * 128) / 256, 256, 0, stream>>>(
      (const f16x4*)zh, (const f16x4*)fh, (const f16x4*)ogh, hin, (float4*)out);
}

// Round 9
// 313.944 us; speedup vs baseline: 1.2717x; 1.2386x over previous
//
#include <hip/hip_runtime.h>
#include <stdint.h>

#define Bdim 16
#define Sdim 4096
#define Hdim 512
#define Mdim (Bdim*Sdim)      // 65536
#define N3   (3*Hdim)         // 1536
#define Kdim 512
#define NCHUNK 64
#define CLEN  (Sdim/NCHUNK)   // 64

typedef __bf16 bf16;
typedef __bf16 bf16x4 __attribute__((ext_vector_type(4)));
typedef __bf16 bf16x8 __attribute__((ext_vector_type(8)));
typedef float  f32x4  __attribute__((ext_vector_type(4)));
typedef _Float16 f16;
typedef _Float16 f16x4 __attribute__((ext_vector_type(4)));
typedef _Float16 f16x8 __attribute__((ext_vector_type(8)));

__device__ __forceinline__ void gload_lds16(const void* g, void* l) {
  __builtin_amdgcn_global_load_lds(
      (const __attribute__((address_space(1))) uint32_t*)g,
      (__attribute__((address_space(3))) uint32_t*)l, 16, 0, 0);
}

// ---------- fp32 -> bf16 convert (vectorized) ----------
__global__ void __launch_bounds__(256) cvt_kernel(const float4* __restrict__ in,
                                                  bf16x4* __restrict__ out, int n4) {
  int i = blockIdx.x * blockDim.x + threadIdx.x;
  if (i >= n4) return;
  float4 v = in[i];
  bf16x4 o;
  o.x = (bf16)v.x; o.y = (bf16)v.y; o.z = (bf16)v.z; o.w = (bf16)v.w;
  out[i] = o;
}

// ====== 256x256 MFMA GEMM, BK=32, 64KB LDS dbuf -> 2 blocks/CU ======
// A: (M,K) bf16 row-major; Wb: (N,K) bf16 row-major. C = A*Wb^T, fused act.
// m97-style simple loop: stage(t+1) -> ds_read(t) -> MFMA -> __syncthreads.
// Cross-block co-scheduling (2 blocks/CU) hides the barrier drains; no
// inline-asm waitcnt anywhere in the K-loop.
// Slot swizzle (16B slots, 4/row): s' = s ^ ((row>>1)&3), at stage source
// AND ds_read (measured 0 bank conflicts in r3-r6).
#define BM 256
#define BN 256
#define BK2 32
#define NT (Kdim/BK2)   // 16

__global__ void __launch_bounds__(512, 2) gemm_act_kernel(
    const bf16* __restrict__ A, const bf16* __restrict__ Wb,
    const float* __restrict__ bias,
    f16* __restrict__ zbuf, f16* __restrict__ fbuf, f16* __restrict__ ogbuf) {
  __shared__ char lds[65536];   // buf t: (t&1)*32768; A 16KB then B 16KB
  const int tid  = threadIdx.x;
  const int wid  = tid >> 6;
  const int lane = tid & 63;
  const int wr = wid >> 2, wc = wid & 3;   // 2(M) x 4(N) waves; wave tile 128x64
  // XCD-chunked bijective swizzle: 1536 blocks = 8 XCDs x 192
  const int bid = blockIdx.x;
  const int wg  = (bid & 7) * 192 + (bid >> 3);
  const int mt = wg / (N3 / BN);
  const int nt = wg % (N3 / BN);           // 6 N-tiles, inner -> A reuse per XCD
  const int row0 = mt * BM;

  const bf16* Ag = A  + (size_t)row0 * Kdim;
  const bf16* Bg = Wb + (size_t)(nt * BN) * Kdim;

  // staging: per tile, A = 256 rows x 4 slots x 16B = 16KB (B same).
  // thread covers chunks c = i*512 + tid (i=0,1) for A and for B.
  // LDS dest linear (c*16); global source pre-swizzled slot ^ ((r>>1)&3).
  uint32_t srcO[2];
  {
    int r_ = tid >> 2, slot = tid & 3;
    #pragma unroll
    for (int i = 0; i < 2; ++i) {
      int row = i * 128 + r_;
      srcO[i] = (uint32_t)(row * Kdim + ((slot ^ ((row >> 1) & 3)) << 3));
    }
  }
  const uint32_t dstBase = (uint32_t)(wid * 1024);  // bytes, wave-uniform (lane*16 implicit)

  // ds_read byte offsets within a 32KB buffer; row stride 64B, kslot = lane>>4
  uint32_t byteA[8], byteB[4];
  {
    int kslot = lane >> 4;
    #pragma unroll
    for (int m = 0; m < 8; ++m) {
      int row = wr * 128 + m * 16 + (lane & 15);
      byteA[m] = (uint32_t)(row * 64 + ((kslot ^ ((row >> 1) & 3)) << 4));
    }
    #pragma unroll
    for (int n = 0; n < 4; ++n) {
      int row = wc * 64 + n * 16 + (lane & 15);
      byteB[n] = (uint32_t)(16384 + row * 64 + ((kslot ^ ((row >> 1) & 3)) << 4));
    }
  }

  f32x4 acc[8][4];
  #pragma unroll
  for (int m = 0; m < 8; ++m)
    #pragma unroll
    for (int n = 0; n < 4; ++n)
      acc[m][n] = (f32x4){0.f, 0.f, 0.f, 0.f};

  // prologue: stage tile 0 into buf0
  {
    char* Ad = lds; char* Bd = lds + 16384;
    #pragma unroll
    for (int i = 0; i < 2; ++i) gload_lds16(Ag + srcO[i], Ad + i * 8192 + dstBase);
    #pragma unroll
    for (int i = 0; i < 2; ++i) gload_lds16(Bg + srcO[i], Bd + i * 8192 + dstBase);
  }
  __syncthreads();

  for (int t = 0; t < NT; ++t) {
    if (t + 1 < NT) {  // stage next tile into other buffer
      char* Ad = lds + ((t + 1) & 1) * 32768; char* Bd = Ad + 16384;
      #pragma unroll
      for (int i = 0; i < 2; ++i)
        gload_lds16(Ag + srcO[i] + (t + 1) * BK2, Ad + i * 8192 + dstBase);
      #pragma unroll
      for (int i = 0; i < 2; ++i)
        gload_lds16(Bg + srcO[i] + (t + 1) * BK2, Bd + i * 8192 + dstBase);
    }
    const char* Ab = lds + (t & 1) * 32768;
    bf16x8 af[8], bfrag[4];
    #pragma unroll
    for (int m = 0; m < 8; ++m) af[m] = *(const bf16x8*)(Ab + byteA[m]);
    #pragma unroll
    for (int n = 0; n < 4; ++n) bfrag[n] = *(const bf16x8*)(Ab + byteB[n]);
    __builtin_amdgcn_s_setprio(1);
    #pragma unroll
    for (int m = 0; m < 8; ++m)
      #pragma unroll
      for (int n = 0; n < 4; ++n)
        acc[m][n] = __builtin_amdgcn_mfma_f32_16x16x32_bf16(af[m], bfrag[n], acc[m][n], 0, 0, 0);
    __builtin_amdgcn_s_setprio(0);
    __syncthreads();  // drain; other resident block fills this stall
  }

  // ---- epilogue: activation, repack via full 64KB LDS, coalesced stores ----
  const int gate = nt >> 1;                 // BN=256 divides each 512-col gate
  const int cbn  = (nt & 1) * 256;
  f16* dst = (gate == 0) ? zbuf : ((gate == 1) ? fbuf : ogbuf);
  float bv[4];
  #pragma unroll
  for (int n = 0; n < 4; ++n)
    bv[n] = bias[gate * Hdim + cbn + wc * 64 + n * 16 + (lane & 15)];

  #pragma unroll
  for (int R = 0; R < 2; ++R) {
    // write: acc m = 4R..4R+3 -> 128 local rows x 512B, swizzled
    #pragma unroll
    for (int m4 = 0; m4 < 4; ++m4) {
      const int m = R * 4 + m4;
      #pragma unroll
      for (int n = 0; n < 4; ++n) {
        int col = wc * 64 + n * 16 + (lane & 15);
        #pragma unroll
        for (int r = 0; r < 4; ++r) {
          int Lrow = wr * 64 + m4 * 16 + (lane >> 4) * 4 + r;
          float y = acc[m][n][r] + bv[n];
          float v;
          if (gate == 0) {                       // tanh(y) = 1 - 2/(e^{2y}+1)
            float e = __expf(2.f * y);
            v = 1.f - 2.f / (e + 1.f);
          } else {                               // sigmoid
            v = 1.f / (1.f + __expf(-y));
          }
          uint32_t byte = (uint32_t)(Lrow * 512 + col * 2) ^ ((uint32_t)(Lrow & 7) << 4);
          *(f16*)(lds + byte) = (f16)v;
        }
      }
    }
    __syncthreads();
    // read + coalesced f16x8 stores
    #pragma unroll
    for (int j = 0; j < 8; ++j) {
      int c = j * 512 + tid;
      int Lrow = c >> 5, col8 = c & 31;
      uint32_t byte = (uint32_t)(Lrow * 512 + col8 * 16) ^ ((uint32_t)(Lrow & 7) << 4);
      f16x8 v = *(const f16x8*)(lds + byte);
      int G = (Lrow >> 6) * 128 + R * 64 + (Lrow & 63);
      *(f16x8*)&dst[(size_t)(row0 + G) * Hdim + cbn + col8 * 8] = v;
    }
    __syncthreads();  // reads retired before next round's writes
  }
}

// ---------- scan pass A: per-chunk composite (P = prod(1-f), Q = local scan) ----------
__global__ void __launch_bounds__(256) scanA_kernel(const f16x4* __restrict__ z4,
                                                    const f16x4* __restrict__ f4,
                                                    float* __restrict__ Pb,
                                                    float* __restrict__ Qb) {
  int u  = blockIdx.x * blockDim.x + threadIdx.x;  // 131072 = NCHUNK*B*128
  int hq = u & 127;
  int bc = u >> 7;
  int b  = bc & (Bdim - 1);
  int c  = bc >> 4;
  size_t base = ((size_t)(b * Sdim + c * CLEN)) * 128 + hq;  // in quads
  float P[4] = {1.f, 1.f, 1.f, 1.f}, Q[4] = {0.f, 0.f, 0.f, 0.f};
  #pragma unroll 4
  for (int s = 0; s < CLEN; ++s) {
    f16x4 fv = f4[base], zv = z4[base];
    #pragma unroll
    for (int j = 0; j < 4; ++j) {
      float f = (float)fv[j];
      Q[j] += f * ((float)zv[j] - Q[j]);
      P[j] *= (1.f - f);
    }
    base += 128;
  }
  int outi = ((c * Bdim + b) << 9) + hq * 4;
  *(float4*)&Pb[outi] = make_float4(P[0], P[1], P[2], P[3]);
  *(float4*)&Qb[outi] = make_float4(Q[0], Q[1], Q[2], Q[3]);
}

// ---------- scan pass B: scan chunk composites -> h_in per chunk + c_last ----------
__global__ void __launch_bounds__(256) scanB_kernel(const float* __restrict__ Pb,
                                                    const float* __restrict__ Qb,
                                                    float* __restrict__ hin,
                                                    float* __restrict__ c_last) {
  int t = blockIdx.x * blockDim.x + threadIdx.x;  // 8192 = B*H
  int h = t & (Hdim - 1), b = t >> 9;
  float hs = 0.f;
  #pragma unroll 8
  for (int c = 0; c < NCHUNK; ++c) {
    hin[c * (Bdim * Hdim) + t] = hs;
    int u = ((c * Bdim + b) << 9) + h;
    hs = Pb[u] * hs + Qb[u];
  }
  c_last[t] = hs;
}

// ---------- scan pass C: rerun chunk with correct h_in, fuse out = og * h ----------
__global__ void __launch_bounds__(256) scanC_kernel(const f16x4* __restrict__ z4,
                                                    const f16x4* __restrict__ f4,
                                                    const f16x4* __restrict__ og4,
                                                    const float* __restrict__ hin,
                                                    float4* __restrict__ out4) {
  int u  = blockIdx.x * blockDim.x + threadIdx.x;
  int hq = u & 127;
  int bc = u >> 7;
  int b  = bc & (Bdim - 1);
  int c  = bc >> 4;
  float4 hv = *(const float4*)&hin[c * (Bdim * Hdim) + b * Hdim + hq * 4];
  float h[4] = {hv.x, hv.y, hv.z, hv.w};
  size_t base = ((size_t)(b * Sdim + c * CLEN)) * 128 + hq;
  #pragma unroll 4
  for (int s = 0; s < CLEN; ++s) {
    f16x4 fv = f4[base], zv = z4[base], ov = og4[base];
    float4 o;
    #pragma unroll
    for (int j = 0; j < 4; ++j) {
      h[j] += (float)fv[j] * ((float)zv[j] - h[j]);
    }
    o.x = (float)ov[0] * h[0]; o.y = (float)ov[1] * h[1];
    o.z = (float)ov[2] * h[2]; o.w = (float)ov[3] * h[3];
    out4[base] = o;
    base += 128;
  }
}

extern "C" void kernel_launch(void* const* d_in, const int* in_sizes, int n_in,
                              void* d_out, int out_size, void* d_ws, size_t ws_size,
                              hipStream_t stream) {
  const float* inp  = (const float*)d_in[0];
  const float* W    = (const float*)d_in[1];
  const float* bias = (const float*)d_in[2];
  float* out = (float*)d_out;

  char* ws = (char*)d_ws;
  // workspace layout (bytes), total ~276 MB
  bf16* Abf = (bf16*)(ws);                   //  67,108,864
  bf16* Wbf = (bf16*)(ws + 67108864);        //   1,572,864
  f16*  zh  = (f16*) (ws + 68681728);        //  67,108,864
  f16*  fh  = (f16*) (ws + 135790592);       //  67,108,864
  f16*  ogh = (f16*) (ws + 202899456);       //  67,108,864
  float* Pb = (float*)(ws + 270008320);      //   2,097,152
  float* Qb = (float*)(ws + 272105472);      //   2,097,152
  float* hin= (float*)(ws + 274202624);      //   2,097,152

  // 1) convert inp and W to bf16
  {
    int n4 = (Mdim * Kdim) / 4;  // 8,388,608
    cvt_kernel<<<n4 / 256, 256, 0, stream>>>((const float4*)inp, (bf16x4*)Abf, n4);
  }
  {
    int n4 = (N3 * Kdim) / 4;    // 196,608
    cvt_kernel<<<n4 / 256, 256, 0, stream>>>((const float4*)W, (bf16x4*)Wbf, n4);
  }
  // 2) GEMM + bias + activations -> fp16 gates (64KB LDS -> 2 blocks/CU)
  gemm_act_kernel<<<(Mdim / BM) * (N3 / BN), 512, 0, stream>>>(Abf, Wbf, bias,
                                                               zh, fh, ogh);
  // 3) chunked linear-recurrence scan
  scanA_kernel<<<(NCHUNK * Bdim * 128) / 256, 256, 0, stream>>>(
      (const f16x4*)zh, (const f16x4*)fh, Pb, Qb);
  scanB_kernel<<<(Bdim * Hdim) / 256, 256, 0, stream>>>(Pb, Qb, hin,
                                                        out + (size_t)Mdim * Hdim);
  scanC_kernel<<<(NCHUNK * Bdim * 128) / 256, 256, 0, stream>>>(
      (const f16x4*)zh, (const f16x4*)fh, (const f16x4*)ogh, hin, (float4*)out);
}